// Round 6
// baseline (343.450 us; speedup 1.0000x reference)
//
#include <hip/hip_runtime.h>
#include <hip/hip_bf16.h>
#include <stdint.h>

typedef __attribute__((ext_vector_type(4))) float f32x4;
typedef __attribute__((ext_vector_type(8))) short s16x8;

__device__ __forceinline__ short f2bf(float f) {
  union { float f; uint32_t u; } v; v.f = f;
  uint32_t r = v.u + 0x7FFFu + ((v.u >> 16) & 1u);
  return (short)(r >> 16);
}

__device__ __forceinline__ void async16(const void* g, void* l) {
  __builtin_amdgcn_global_load_lds(
      (const __attribute__((address_space(1))) void*)g,
      (__attribute__((address_space(3))) void*)l, 16, 0, 0);
}

// ---------------- cast x (fp32 -> bf16), 8 elems/thread ----------------
__global__ __launch_bounds__(256) void k_cast_bf16(const float* __restrict__ in,
                                                   short* __restrict__ out, int n8) {
  int i = blockIdx.x * 256 + threadIdx.x;
  if (i >= n8) return;
  const float4* p = (const float4*)in + (size_t)i * 2;
  float4 a = p[0], b = p[1];
  s16x8 o;
  o[0] = f2bf(a.x); o[1] = f2bf(a.y); o[2] = f2bf(a.z); o[3] = f2bf(a.w);
  o[4] = f2bf(b.x); o[5] = f2bf(b.y); o[6] = f2bf(b.z); o[7] = f2bf(b.w);
  ((s16x8*)out)[i] = o;
}

// -------- LDS-tiled transpose+cast: out[n][k] = bf16(in[k][n]) --------
__global__ __launch_bounds__(256) void k_transpose_cast(const float* __restrict__ in,
                                                        short* __restrict__ out,
                                                        int K, int N) {
  __shared__ float tile[64][65];
  const int bx = blockIdx.x;  // n-tile
  const int by = blockIdx.y;  // k-tile
  const int tx = threadIdx.x & 63, ty = threadIdx.x >> 6;
#pragma unroll
  for (int r = ty; r < 64; r += 4)
    tile[r][tx] = in[(size_t)(by * 64 + r) * N + bx * 64 + tx];
  __syncthreads();
#pragma unroll
  for (int r = ty; r < 64; r += 4)
    out[(size_t)(bx * 64 + r) * K + by * 64 + tx] = f2bf(tile[tx][r]);
}

// ===== persistent 256x256 8-phase bf16 GEMM — round-2 inner loop, fixed bm =====
// Grid = 256 (1 block/CU). Block b: bm = b (A panel L2-resident, HBM-read once),
// bn walks 0..ntiles-1. Global step s = j*NT + T runs the proven round-2
// schedule seamlessly across tile boundaries:
//   ph0/1: issue A(s+1)   ph2/3: issue B(s+2)   tail: vmcnt(4)
// Epilogue stores overlap the next tile's K-loop (no waits on stores).
#define TILE_SH 16384  // 256*64 shorts per tile

template <bool F32OUT>
__global__ __launch_bounds__(512, 2) void k_gemm256p(const short* __restrict__ A,
                                                     const short* __restrict__ Bw,
                                                     const float* __restrict__ bias,
                                                     void* __restrict__ C,
                                                     int N, int K, int ntiles) {
  __shared__ short lds[2 * 2 * TILE_SH];  // 128 KiB
  const int t = threadIdx.x;
  const int w = t >> 6, l = t & 63;
  const int wm = w >> 2, wn = w & 3;
  const int bm = blockIdx.x;

  const int NT = K >> 6;            // 8
  const int NS = ntiles * NT;

  auto stage = [&](const short* __restrict__ G, int row0, int kt, short* dst) {
#pragma unroll
    for (int L = 0; L < 2; ++L) {
      int cw = L * 512 + (t & ~63);
      int c = cw + l;
      int r = c >> 3, s = c & 7;
      async16(G + (size_t)(row0 + r) * K + kt + ((s ^ (r & 7)) << 3), dst + cw * 8);
    }
  };
  auto issueA = [&](int step, int hf) {
    int kt = step & 7;  // NT == 8
    stage(A, bm * 256 + hf * 128, kt * 64, lds + (kt & 1) * 32768 + hf * 8192);
  };
  auto issueB = [&](int step, int hf) {
    int bnv = step >> 3, kt = step & 7;
    stage(Bw, bnv * 256 + hf * 128, kt * 64, lds + (kt & 1) * 32768 + TILE_SH + hf * 8192);
  };

  const int g = l >> 4, v = l & 7;
  int ofsA[2], ofsB[2];
#pragma unroll
  for (int ks = 0; ks < 2; ++ks) {
    ofsA[ks] = (wm * 128 + (l & 15)) * 64 + (((ks * 4 + g) ^ v) << 3);
    ofsB[ks] = (wn * 64 + (l & 15)) * 64 + (((ks * 4 + g) ^ v) << 3);
  }

  f32x4 acc[8][4] = {};
  s16x8 bfr[4][2];

  // prologue (round-2): B(0), A(0), B(1) -> 12 loads, vmcnt(4) -> A0,B0 landed
  issueB(0, 0); issueB(0, 1); issueA(0, 0); issueA(0, 1);
  issueB(1, 0); issueB(1, 1);
  asm volatile("s_waitcnt vmcnt(4)" ::: "memory");
  __builtin_amdgcn_s_barrier();

#define PHASE(AI0, STAGE_STMT, TAIL_STMT)                                                                      \
  {                                                                                                            \
    s16x8 a00 = *(const s16x8*)(Ab + ofsA[0] + (AI0) * 1024);                                                  \
    s16x8 a01 = *(const s16x8*)(Ab + ofsA[1] + (AI0) * 1024);                                                  \
    s16x8 a10 = *(const s16x8*)(Ab + ofsA[0] + ((AI0) + 1) * 1024);                                            \
    s16x8 a11 = *(const s16x8*)(Ab + ofsA[1] + ((AI0) + 1) * 1024);                                            \
    STAGE_STMT;                                                                                                \
    __builtin_amdgcn_s_barrier();                                                                              \
    asm volatile("s_waitcnt lgkmcnt(0)" ::: "memory");                                                         \
    __builtin_amdgcn_s_setprio(1);                                                                             \
    _Pragma("unroll")                                                                                          \
    for (int nj = 0; nj < 4; ++nj) {                                                                           \
      acc[(AI0)][nj] = __builtin_amdgcn_mfma_f32_16x16x32_bf16(a00, bfr[nj][0], acc[(AI0)][nj], 0, 0, 0);      \
      acc[(AI0)][nj] = __builtin_amdgcn_mfma_f32_16x16x32_bf16(a01, bfr[nj][1], acc[(AI0)][nj], 0, 0, 0);      \
      acc[(AI0) + 1][nj] = __builtin_amdgcn_mfma_f32_16x16x32_bf16(a10, bfr[nj][0], acc[(AI0) + 1][nj], 0, 0, 0); \
      acc[(AI0) + 1][nj] = __builtin_amdgcn_mfma_f32_16x16x32_bf16(a11, bfr[nj][1], acc[(AI0) + 1][nj], 0, 0, 0); \
    }                                                                                                          \
    __builtin_amdgcn_s_setprio(0);                                                                             \
    TAIL_STMT;                                                                                                 \
    __builtin_amdgcn_s_barrier();                                                                              \
  }

  for (int j = 0; j < ntiles; ++j) {
    for (int T = 0; T < NT; ++T) {
      const int s = j * NT + T;
      const int s1 = s + 1, s2 = s + 2;
      const short* Ab = lds + (T & 1) * 32768;
      const short* Bb = Ab + TILE_SH;
#pragma unroll
      for (int nj = 0; nj < 4; ++nj)
#pragma unroll
        for (int ks = 0; ks < 2; ++ks)
          bfr[nj][ks] = *(const s16x8*)(Bb + ofsB[ks] + nj * 1024);

      PHASE(0, if (s1 < NS) issueA(s1, 0), );
      PHASE(2, if (s1 < NS) issueA(s1, 1), );
      PHASE(4, if (s2 < NS) issueB(s2, 0), );
      PHASE(6, if (s2 < NS) issueB(s2, 1),
            if (s2 < NS) { asm volatile("s_waitcnt vmcnt(4)" ::: "memory"); }
            else if (s1 < NS) { asm volatile("s_waitcnt vmcnt(0)" ::: "memory"); });
    }

    // epilogue tile j: stores overlap next tile's K-loop
#pragma unroll
    for (int ai = 0; ai < 8; ++ai)
#pragma unroll
      for (int nj = 0; nj < 4; ++nj) {
        int col = j * 256 + wn * 64 + nj * 16 + (l & 15);
        float bv = bias[col];
#pragma unroll
        for (int r = 0; r < 4; ++r) {
          int row = bm * 256 + wm * 128 + ai * 16 + (l >> 4) * 4 + r;
          float vv = acc[ai][nj][r] + bv;
          if (F32OUT)
            ((float*)C)[(size_t)row * N + col] = vv;
          else
            ((short*)C)[(size_t)row * N + col] = f2bf(vv);
        }
      }
#pragma unroll
    for (int ai = 0; ai < 8; ++ai)
#pragma unroll
      for (int nj = 0; nj < 4; ++nj)
        acc[ai][nj] = (f32x4){0.f, 0.f, 0.f, 0.f};
  }
#undef PHASE
}

// ---------------- fused window attention: 1 wave per (b,h) ----------------
__global__ __launch_bounds__(256) void k_attn(const short* __restrict__ qkv,
                                              const float* __restrict__ mask,
                                              const float* __restrict__ bias_table,
                                              short* __restrict__ Y) {
  __shared__ float mask_lds[64 * 64];
  __shared__ float bias_lds[4][128];
  __shared__ short p_lds[4][64][72];

  const int t = threadIdx.x, wv = t >> 6, ln = t & 63;
  const int b = blockIdx.x;
  const int h = blockIdx.y * 4 + wv;

  const float4* mk = (const float4*)(mask + (size_t)(b & 63) * 4096);
#pragma unroll
  for (int u = 0; u < 4; ++u)
    ((float4*)mask_lds)[t + 256 * u] = mk[t + 256 * u];
  for (int u = ln; u < 127; u += 64) bias_lds[wv][u] = bias_table[u * 16 + h];
  __syncthreads();

  const short* qb = qkv + (size_t)b * 64 * 1536 + h * 32;

  s16x8 qf[4], kf[4];
#pragma unroll
  for (int i = 0; i < 4; ++i) {
    qf[i] = *(const s16x8*)(qb + (size_t)(16 * i + (ln & 15)) * 1536 + (ln >> 4) * 8);
    kf[i] = *(const s16x8*)(qb + (size_t)(16 * i + (ln & 15)) * 1536 + 512 + (ln >> 4) * 8);
  }
  f32x4 s[4][4] = {};
#pragma unroll
  for (int i = 0; i < 4; ++i)
#pragma unroll
    for (int j = 0; j < 4; ++j)
      s[i][j] = __builtin_amdgcn_mfma_f32_16x16x32_bf16(qf[i], kf[j], s[i][j], 0, 0, 0);

  const float scale = 0.17677669529663687f;
#pragma unroll
  for (int i = 0; i < 4; ++i)
#pragma unroll
    for (int r = 0; r < 4; ++r) {
      int nn = 16 * i + (ln >> 4) * 4 + r;
      float vals[4];
      float vmax = -1e30f;
#pragma unroll
      for (int j = 0; j < 4; ++j) {
        int mm = 16 * j + (ln & 15);
        float x = s[i][j][r] * scale + bias_lds[wv][nn - mm + 63] + mask_lds[nn * 64 + mm];
        vals[j] = x;
        vmax = fmaxf(vmax, x);
      }
#pragma unroll
      for (int d = 1; d < 16; d <<= 1) vmax = fmaxf(vmax, __shfl_xor(vmax, d, 64));
      float sum = 0.f;
#pragma unroll
      for (int j = 0; j < 4; ++j) {
        float p = __expf(vals[j] - vmax);
        vals[j] = p;
        sum += p;
      }
#pragma unroll
      for (int d = 1; d < 16; d <<= 1) sum += __shfl_xor(sum, d, 64);
      float rsv = 1.0f / sum;
#pragma unroll
      for (int j = 0; j < 4; ++j)
        p_lds[wv][nn][16 * j + (ln & 15)] = f2bf(vals[j] * rsv);
    }

  const short* vg = qb + 1024;
  f32x4 o[4][2] = {};
#pragma unroll
  for (int kk = 0; kk < 2; ++kk) {
    s16x8 pa[4];
#pragma unroll
    for (int i2 = 0; i2 < 4; ++i2)
      pa[i2] = *(const s16x8*)&p_lds[wv][16 * i2 + (ln & 15)][kk * 32 + (ln >> 4) * 8];
#pragma unroll
    for (int j2 = 0; j2 < 2; ++j2) {
      s16x8 vf;
#pragma unroll
      for (int jj = 0; jj < 8; ++jj)
        vf[jj] = vg[(size_t)(kk * 32 + (ln >> 4) * 8 + jj) * 1536 + 16 * j2 + (ln & 15)];
#pragma unroll
      for (int i2 = 0; i2 < 4; ++i2)
        o[i2][j2] = __builtin_amdgcn_mfma_f32_16x16x32_bf16(pa[i2], vf, o[i2][j2], 0, 0, 0);
    }
  }

#pragma unroll
  for (int i2 = 0; i2 < 4; ++i2)
#pragma unroll
    for (int j2 = 0; j2 < 2; ++j2)
#pragma unroll
      for (int r = 0; r < 4; ++r) {
        int n = 16 * i2 + (ln >> 4) * 4 + r;
        int d = 16 * j2 + (ln & 15);
        int rr = h * 64 + (b >> 4);
        int ss = (b & 15) * 4 + (n >> 4);
        int cc = (n & 15) * 32 + d;
        Y[((size_t)rr * 64 + ss) * 512 + cc] = f2bf(o[i2][j2][r]);
      }
}

extern "C" void kernel_launch(void* const* d_in, const int* in_sizes, int n_in,
                              void* d_out, int out_size, void* d_ws, size_t ws_size,
                              hipStream_t stream) {
  const float* x      = (const float*)d_in[0];
  const float* mask   = (const float*)d_in[1];
  const float* qkv_w  = (const float*)d_in[2];
  const float* qkv_b  = (const float*)d_in[3];
  const float* proj_w = (const float*)d_in[4];
  const float* proj_b = (const float*)d_in[5];
  const float* btab   = (const float*)d_in[6];
  float* out = (float*)d_out;

  char* w = (char*)d_ws;
  short* qkv_ws = (short*)w;                                             // 192 MiB
  short* xbf    = (short*)(w + (size_t)65536 * 1536 * 2);                // 64 MiB
  short* Y      = xbf;                                                   // reuse after GEMM1
  short* wT     = (short*)(w + (size_t)65536 * 1536 * 2 + (size_t)65536 * 512 * 2);
  short* projT  = wT + 1536 * 512;

  k_cast_bf16<<<16384, 256, 0, stream>>>(x, xbf, 33554432 / 8);
  k_transpose_cast<<<dim3(24, 8), 256, 0, stream>>>(qkv_w, wT, 512, 1536);
  k_transpose_cast<<<dim3(8, 8), 256, 0, stream>>>(proj_w, projT, 512, 512);
  k_gemm256p<false><<<256, 512, 0, stream>>>(xbf, wT, qkv_b, qkv_ws, 1536, 512, 6);
  k_attn<<<dim3(1024, 4), 256, 0, stream>>>(qkv_ws, mask, btab, Y);
  k_gemm256p<true><<<256, 512, 0, stream>>>(Y, projT, proj_b, out, 512, 512, 2);
}

// Round 7
// 306.696 us; speedup vs baseline: 1.1198x; 1.1198x over previous
//
#include <hip/hip_runtime.h>
#include <hip/hip_bf16.h>
#include <stdint.h>

typedef __attribute__((ext_vector_type(4))) float f32x4;
typedef __attribute__((ext_vector_type(8))) short s16x8;

__device__ __forceinline__ short f2bf(float f) {
  union { float f; uint32_t u; } v; v.f = f;
  uint32_t r = v.u + 0x7FFFu + ((v.u >> 16) & 1u);
  return (short)(r >> 16);
}

__device__ __forceinline__ void async16(const void* g, void* l) {
  __builtin_amdgcn_global_load_lds(
      (const __attribute__((address_space(1))) void*)g,
      (__attribute__((address_space(3))) void*)l, 16, 0, 0);
}

// ---------------- cast x (fp32 -> bf16), 8 elems/thread ----------------
__global__ __launch_bounds__(256) void k_cast_bf16(const float* __restrict__ in,
                                                   short* __restrict__ out, int n8) {
  int i = blockIdx.x * 256 + threadIdx.x;
  if (i >= n8) return;
  const float4* p = (const float4*)in + (size_t)i * 2;
  float4 a = p[0], b = p[1];
  s16x8 o;
  o[0] = f2bf(a.x); o[1] = f2bf(a.y); o[2] = f2bf(a.z); o[3] = f2bf(a.w);
  o[4] = f2bf(b.x); o[5] = f2bf(b.y); o[6] = f2bf(b.z); o[7] = f2bf(b.w);
  ((s16x8*)out)[i] = o;
}

// -------- LDS-tiled transpose+cast: out[n][k] = bf16(in[k][n]) --------
__global__ __launch_bounds__(256) void k_transpose_cast(const float* __restrict__ in,
                                                        short* __restrict__ out,
                                                        int K, int N) {
  __shared__ float tile[64][65];
  const int bx = blockIdx.x;  // n-tile
  const int by = blockIdx.y;  // k-tile
  const int tx = threadIdx.x & 63, ty = threadIdx.x >> 6;
#pragma unroll
  for (int r = ty; r < 64; r += 4)
    tile[r][tx] = in[(size_t)(by * 64 + r) * N + bx * 64 + tx];
  __syncthreads();
#pragma unroll
  for (int r = ty; r < 64; r += 4)
    out[(size_t)(bx * 64 + r) * K + by * 64 + tx] = f2bf(tile[tx][r]);
}

// ===== persistent 256x256 8-phase bf16 GEMM — round-2 tile ORDER preserved =====
// Grid = 256 (1 block/CU). Block b at round j works tile tau = swz(b) + 256*j,
// swz(b) = (b&7)*32 + (b>>3): the concurrent tile frontier equals round-2's
// XCD-swizzled grid (A panels shared 6-way in each XCD's L2), while the proven
// round-2 schedule (A 1-ahead ph0/1, B 2-ahead ph2/3, vmcnt(4)) runs seamlessly
// across tile boundaries. Epilogue stores overlap the next tile's K-loop.
#define TILE_SH 16384  // 256*64 shorts per tile

template <bool F32OUT, int NBN>
__global__ __launch_bounds__(512, 2) void k_gemm256p(const short* __restrict__ A,
                                                     const short* __restrict__ Bw,
                                                     const float* __restrict__ bias,
                                                     void* __restrict__ C,
                                                     int N, int K, int nrounds) {
  __shared__ short lds[2 * 2 * TILE_SH];  // 128 KiB
  const int t = threadIdx.x;
  const int w = t >> 6, l = t & 63;
  const int wm = w >> 2, wn = w & 3;
  const int swz = (((int)blockIdx.x & 7) << 5) + ((int)blockIdx.x >> 3);

  const int NT = 8;  // K==512
  const int NS = nrounds * NT;

  auto stage = [&](const short* __restrict__ G, int row0, int kt, short* dst) {
#pragma unroll
    for (int L = 0; L < 2; ++L) {
      int cw = L * 512 + (t & ~63);
      int c = cw + l;
      int r = c >> 3, s = c & 7;
      async16(G + (size_t)(row0 + r) * K + kt + ((s ^ (r & 7)) << 3), dst + cw * 8);
    }
  };
  auto issueA = [&](int step, int bmv, int hf) {
    int kt = step & 7;
    stage(A, bmv * 256 + hf * 128, kt * 64, lds + (kt & 1) * 32768 + hf * 8192);
  };
  auto issueB = [&](int step, int bnv, int hf) {
    int kt = step & 7;
    stage(Bw, bnv * 256 + hf * 128, kt * 64, lds + (kt & 1) * 32768 + TILE_SH + hf * 8192);
  };

  const int g = l >> 4, v = l & 7;
  int ofsA[2], ofsB[2];
#pragma unroll
  for (int ks = 0; ks < 2; ++ks) {
    ofsA[ks] = (wm * 128 + (l & 15)) * 64 + (((ks * 4 + g) ^ v) << 3);
    ofsB[ks] = (wn * 64 + (l & 15)) * 64 + (((ks * 4 + g) ^ v) << 3);
  }

  f32x4 acc[8][4] = {};
  s16x8 bfr[4][2];

  // prologue: tile 0 coords; B(0), A(0), B(1) -> 12 loads; vmcnt(4)
  {
    const int bm0 = swz / NBN, bn0 = swz % NBN;
    issueB(0, bn0, 0); issueB(0, bn0, 1);
    issueA(0, bm0, 0); issueA(0, bm0, 1);
    issueB(1, bn0, 0); issueB(1, bn0, 1);
  }
  asm volatile("s_waitcnt vmcnt(4)" ::: "memory");
  __builtin_amdgcn_s_barrier();

#define PHASE(AI0, STAGE_STMT, TAIL_STMT)                                                                      \
  {                                                                                                            \
    s16x8 a00 = *(const s16x8*)(Ab + ofsA[0] + (AI0) * 1024);                                                  \
    s16x8 a01 = *(const s16x8*)(Ab + ofsA[1] + (AI0) * 1024);                                                  \
    s16x8 a10 = *(const s16x8*)(Ab + ofsA[0] + ((AI0) + 1) * 1024);                                            \
    s16x8 a11 = *(const s16x8*)(Ab + ofsA[1] + ((AI0) + 1) * 1024);                                            \
    STAGE_STMT;                                                                                                \
    __builtin_amdgcn_s_barrier();                                                                              \
    asm volatile("s_waitcnt lgkmcnt(0)" ::: "memory");                                                         \
    __builtin_amdgcn_s_setprio(1);                                                                             \
    _Pragma("unroll")                                                                                          \
    for (int nj = 0; nj < 4; ++nj) {                                                                           \
      acc[(AI0)][nj] = __builtin_amdgcn_mfma_f32_16x16x32_bf16(a00, bfr[nj][0], acc[(AI0)][nj], 0, 0, 0);      \
      acc[(AI0)][nj] = __builtin_amdgcn_mfma_f32_16x16x32_bf16(a01, bfr[nj][1], acc[(AI0)][nj], 0, 0, 0);      \
      acc[(AI0) + 1][nj] = __builtin_amdgcn_mfma_f32_16x16x32_bf16(a10, bfr[nj][0], acc[(AI0) + 1][nj], 0, 0, 0); \
      acc[(AI0) + 1][nj] = __builtin_amdgcn_mfma_f32_16x16x32_bf16(a11, bfr[nj][1], acc[(AI0) + 1][nj], 0, 0, 0); \
    }                                                                                                          \
    __builtin_amdgcn_s_setprio(0);                                                                             \
    TAIL_STMT;                                                                                                 \
    __builtin_amdgcn_s_barrier();                                                                              \
  }

  for (int j = 0; j < nrounds; ++j) {
    const int tauc = swz + (j << 8);
    const int bmc = tauc / NBN, bnc = tauc % NBN;
    for (int T = 0; T < NT; ++T) {
      const int s = (j << 3) + T;
      const int s1 = s + 1, s2 = s + 2;
      // coords of the tiles owning steps s1, s2
      const int tau1 = swz + (((s1) >> 3) << 8);
      const int tau2 = swz + (((s2) >> 3) << 8);
      const int bm1 = tau1 / NBN;
      const int bn2 = tau2 % NBN;
      const short* Ab = lds + (T & 1) * 32768;
      const short* Bb = Ab + TILE_SH;
#pragma unroll
      for (int nj = 0; nj < 4; ++nj)
#pragma unroll
        for (int ks = 0; ks < 2; ++ks)
          bfr[nj][ks] = *(const s16x8*)(Bb + ofsB[ks] + nj * 1024);

      PHASE(0, if (s1 < NS) issueA(s1, bm1, 0), );
      PHASE(2, if (s1 < NS) issueA(s1, bm1, 1), );
      PHASE(4, if (s2 < NS) issueB(s2, bn2, 0), );
      PHASE(6, if (s2 < NS) issueB(s2, bn2, 1),
            if (s2 < NS) { asm volatile("s_waitcnt vmcnt(4)" ::: "memory"); }
            else if (s1 < NS) { asm volatile("s_waitcnt vmcnt(0)" ::: "memory"); });
    }

    // epilogue tile j: stores overlap next tile's K-loop
#pragma unroll
    for (int ai = 0; ai < 8; ++ai)
#pragma unroll
      for (int nj = 0; nj < 4; ++nj) {
        int col = bnc * 256 + wn * 64 + nj * 16 + (l & 15);
        float bv = bias[col];
#pragma unroll
        for (int r = 0; r < 4; ++r) {
          int row = bmc * 256 + wm * 128 + ai * 16 + (l >> 4) * 4 + r;
          float vv = acc[ai][nj][r] + bv;
          if (F32OUT)
            ((float*)C)[(size_t)row * N + col] = vv;
          else
            ((short*)C)[(size_t)row * N + col] = f2bf(vv);
        }
      }
#pragma unroll
    for (int ai = 0; ai < 8; ++ai)
#pragma unroll
      for (int nj = 0; nj < 4; ++nj)
        acc[ai][nj] = (f32x4){0.f, 0.f, 0.f, 0.f};
  }
#undef PHASE
}

// ---------------- fused window attention: 1 wave per (b,h) ----------------
__global__ __launch_bounds__(256) void k_attn(const short* __restrict__ qkv,
                                              const float* __restrict__ mask,
                                              const float* __restrict__ bias_table,
                                              short* __restrict__ Y) {
  __shared__ float mask_lds[64 * 64];
  __shared__ float bias_lds[4][128];
  __shared__ short p_lds[4][64][72];

  const int t = threadIdx.x, wv = t >> 6, ln = t & 63;
  const int b = blockIdx.x;
  const int h = blockIdx.y * 4 + wv;

  const float4* mk = (const float4*)(mask + (size_t)(b & 63) * 4096);
#pragma unroll
  for (int u = 0; u < 4; ++u)
    ((float4*)mask_lds)[t + 256 * u] = mk[t + 256 * u];
  for (int u = ln; u < 127; u += 64) bias_lds[wv][u] = bias_table[u * 16 + h];
  __syncthreads();

  const short* qb = qkv + (size_t)b * 64 * 1536 + h * 32;

  s16x8 qf[4], kf[4];
#pragma unroll
  for (int i = 0; i < 4; ++i) {
    qf[i] = *(const s16x8*)(qb + (size_t)(16 * i + (ln & 15)) * 1536 + (ln >> 4) * 8);
    kf[i] = *(const s16x8*)(qb + (size_t)(16 * i + (ln & 15)) * 1536 + 512 + (ln >> 4) * 8);
  }
  f32x4 s[4][4] = {};
#pragma unroll
  for (int i = 0; i < 4; ++i)
#pragma unroll
    for (int j = 0; j < 4; ++j)
      s[i][j] = __builtin_amdgcn_mfma_f32_16x16x32_bf16(qf[i], kf[j], s[i][j], 0, 0, 0);

  const float scale = 0.17677669529663687f;
#pragma unroll
  for (int i = 0; i < 4; ++i)
#pragma unroll
    for (int r = 0; r < 4; ++r) {
      int nn = 16 * i + (ln >> 4) * 4 + r;
      float vals[4];
      float vmax = -1e30f;
#pragma unroll
      for (int j = 0; j < 4; ++j) {
        int mm = 16 * j + (ln & 15);
        float x = s[i][j][r] * scale + bias_lds[wv][nn - mm + 63] + mask_lds[nn * 64 + mm];
        vals[j] = x;
        vmax = fmaxf(vmax, x);
      }
#pragma unroll
      for (int d = 1; d < 16; d <<= 1) vmax = fmaxf(vmax, __shfl_xor(vmax, d, 64));
      float sum = 0.f;
#pragma unroll
      for (int j = 0; j < 4; ++j) {
        float p = __expf(vals[j] - vmax);
        vals[j] = p;
        sum += p;
      }
#pragma unroll
      for (int d = 1; d < 16; d <<= 1) sum += __shfl_xor(sum, d, 64);
      float rsv = 1.0f / sum;
#pragma unroll
      for (int j = 0; j < 4; ++j)
        p_lds[wv][nn][16 * j + (ln & 15)] = f2bf(vals[j] * rsv);
    }

  const short* vg = qb + 1024;
  f32x4 o[4][2] = {};
#pragma unroll
  for (int kk = 0; kk < 2; ++kk) {
    s16x8 pa[4];
#pragma unroll
    for (int i2 = 0; i2 < 4; ++i2)
      pa[i2] = *(const s16x8*)&p_lds[wv][16 * i2 + (ln & 15)][kk * 32 + (ln >> 4) * 8];
#pragma unroll
    for (int j2 = 0; j2 < 2; ++j2) {
      s16x8 vf;
#pragma unroll
      for (int jj = 0; jj < 8; ++jj)
        vf[jj] = vg[(size_t)(kk * 32 + (ln >> 4) * 8 + jj) * 1536 + 16 * j2 + (ln & 15)];
#pragma unroll
      for (int i2 = 0; i2 < 4; ++i2)
        o[i2][j2] = __builtin_amdgcn_mfma_f32_16x16x32_bf16(pa[i2], vf, o[i2][j2], 0, 0, 0);
    }
  }

#pragma unroll
  for (int i2 = 0; i2 < 4; ++i2)
#pragma unroll
    for (int j2 = 0; j2 < 2; ++j2)
#pragma unroll
      for (int r = 0; r < 4; ++r) {
        int n = 16 * i2 + (ln >> 4) * 4 + r;
        int d = 16 * j2 + (ln & 15);
        int rr = h * 64 + (b >> 4);
        int ss = (b & 15) * 4 + (n >> 4);
        int cc = (n & 15) * 32 + d;
        Y[((size_t)rr * 64 + ss) * 512 + cc] = f2bf(o[i2][j2][r]);
      }
}

extern "C" void kernel_launch(void* const* d_in, const int* in_sizes, int n_in,
                              void* d_out, int out_size, void* d_ws, size_t ws_size,
                              hipStream_t stream) {
  const float* x      = (const float*)d_in[0];
  const float* mask   = (const float*)d_in[1];
  const float* qkv_w  = (const float*)d_in[2];
  const float* qkv_b  = (const float*)d_in[3];
  const float* proj_w = (const float*)d_in[4];
  const float* proj_b = (const float*)d_in[5];
  const float* btab   = (const float*)d_in[6];
  float* out = (float*)d_out;

  char* w = (char*)d_ws;
  short* qkv_ws = (short*)w;                                             // 192 MiB
  short* xbf    = (short*)(w + (size_t)65536 * 1536 * 2);                // 64 MiB
  short* Y      = xbf;                                                   // reuse after GEMM1
  short* wT     = (short*)(w + (size_t)65536 * 1536 * 2 + (size_t)65536 * 512 * 2);
  short* projT  = wT + 1536 * 512;

  k_cast_bf16<<<16384, 256, 0, stream>>>(x, xbf, 33554432 / 8);
  k_transpose_cast<<<dim3(24, 8), 256, 0, stream>>>(qkv_w, wT, 512, 1536);
  k_transpose_cast<<<dim3(8, 8), 256, 0, stream>>>(proj_w, projT, 512, 512);
  k_gemm256p<false, 6><<<256, 512, 0, stream>>>(xbf, wT, qkv_b, qkv_ws, 1536, 512, 6);
  k_attn<<<dim3(1024, 4), 256, 0, stream>>>(qkv_ws, mask, btab, Y);
  k_gemm256p<true, 2><<<256, 512, 0, stream>>>(Y, projT, proj_b, out, 512, 512, 2);
}